// Round 3
// baseline (990.442 us; speedup 1.0000x reference)
//
#include <hip/hip_runtime.h>
#include <math.h>

#define Bdim 256
#define Sdim 512
#define Hdim 1024
#define Wdim 64
#define BK 32
#define JTILE 256
#define NJT 4
#define MTILE 128
#define KC 4
#define NJT2 8      // MFMA path: 8 j-tiles of 128

typedef __attribute__((ext_vector_type(8))) short bf16x8;
typedef __attribute__((ext_vector_type(4))) float f32x4;

// ws layout (floats):
//   [0, 131072)          scores [NJT2][B][W]   (fallback uses first 4 slots)
//   [+,  1048576)        hcw partials [KC][B][H]
//   [+,  1048576)        wsp: W2 bf16 hi/lo, tiled+swizzled [8 jt][32 kc][128 jr][8 slot][16B]
//   [+, 16777216)        apre: A bf16 hi/lo, tiled+swizzled [64 bg][32 kc][256 r][8 slot][16B]
#define WS_SCORES_F (NJT2 * Bdim * Wdim)
#define WS_PART_F   (KC * Bdim * Hdim)
#define WS_WSP_F    (Hdim * Hdim / 2)
#define WS_APRE_F   (Bdim * Wdim * Hdim)
#define WS_NEED_BYTES   ((size_t)(WS_SCORES_F + WS_PART_F) * 4)
#define WS_MFMA_BYTES   ((size_t)(WS_SCORES_F + WS_PART_F + WS_WSP_F + WS_APRE_F) * 4)

// old fp32 path LDS geometry
#define ASTRIDE 140
#define AS_F (BK * ASTRIDE)
#define SMEM_F (AS_F + BK * JTILE)
#define HC0_OFF 0
#define HCW_OFF 2048
#define VS_OFF  2560

#if defined(__has_builtin)
#if __has_builtin(__builtin_amdgcn_global_load_lds)
#define HAS_GLL 1
#endif
#endif
#ifndef HAS_GLL
#define HAS_GLL 0
#endif

__device__ __forceinline__ void gll16(const void* g, void* l) {
#if HAS_GLL
  __builtin_amdgcn_global_load_lds(
      (const __attribute__((address_space(1))) void*)g,
      (__attribute__((address_space(3))) void*)l, 16, 0, 0);
#endif
}

// ---------------------------------------------------------------------------
// Kernel P1: split W2 (= Wa[:, H:2H]) into bf16 hi/lo, tiled+swizzled:
// byte addr = ((jt*32+kc)*128 + jr)*128 + physslot*16 + (t&1)*8
// physslot(hi) = ((t>>1)&3) ^ (jr&7); physslot(lo) = (((t>>1)&3)+4) ^ (jr&7)
// ---------------------------------------------------------------------------
__global__ __launch_bounds__(256) void k_wsplit(
    const float* __restrict__ Wa, unsigned short* __restrict__ wsp)
{
  const int j = blockIdx.x;            // 0..1023
  const int t = threadIdx.x;           // k = 4t..4t+3
  const int jt = j >> 7, jr = j & 127;
  const float4 xv = *(const float4*)(Wa + (size_t)j * (2 * Hdim) + Hdim + 4 * t);
  unsigned short h[4], l[4];
  #pragma unroll
  for (int e = 0; e < 4; ++e) {
    const float x = ((const float*)&xv)[e];
    const unsigned u = __float_as_uint(x);
    const float hif = __uint_as_float(u & 0xFFFF0000u);
    h[e] = (unsigned short)(u >> 16);
    l[e] = (unsigned short)(__float_as_uint(x - hif) >> 16);
  }
  const int kc = t >> 3;
  const int ls = (t >> 1) & 3;
  const int sw = jr & 7;
  char* base = (char*)wsp + (((size_t)(jt * 32 + kc) * 128 + jr) << 7) + (t & 1) * 8;
  *(ushort4*)(base + ((ls ^ sw) << 4))       = make_ushort4(h[0], h[1], h[2], h[3]);
  *(ushort4*)(base + (((ls + 4) ^ sw) << 4)) = make_ushort4(l[0], l[1], l[2], l[3]);
}

// ---------------------------------------------------------------------------
// Kernel P2: gather A rows (slen window), split to bf16 hi/lo, tiled+swizzled:
// byte addr = ((bg*32+kc)*256 + r)*128 + physslot*16 + (t&1)*8, r = global row & 255
// grid (64 w, 256 b), block 256 (thread t -> k=4t..4t+3), coalesced input reads.
// ---------------------------------------------------------------------------
__global__ __launch_bounds__(256) void k_aprep(
    const float* __restrict__ inputs, const int* __restrict__ slen,
    unsigned short* __restrict__ apre)
{
  const int w = blockIdx.x, b = blockIdx.y;
  const int t = threadIdx.x;
  const int gr = b * 64 + w;
  const int r = gr & 255, bg = gr >> 8;
  const int sl = slen[b];
  const float4 xv = *(const float4*)(inputs + ((size_t)b * Sdim + sl - Wdim + w) * Hdim + 4 * t);
  unsigned short h[4], l[4];
  #pragma unroll
  for (int e = 0; e < 4; ++e) {
    const float x = ((const float*)&xv)[e];
    const unsigned u = __float_as_uint(x);
    const float hif = __uint_as_float(u & 0xFFFF0000u);
    h[e] = (unsigned short)(u >> 16);
    l[e] = (unsigned short)(__float_as_uint(x - hif) >> 16);
  }
  const int kc = t >> 3;
  const int ls = (t >> 1) & 3;
  const int sw = r & 7;
  char* base = (char*)apre + (((size_t)(bg * 32 + kc) * 256 + r) << 7) + (t & 1) * 8;
  *(ushort4*)(base + ((ls ^ sw) << 4))       = make_ushort4(h[0], h[1], h[2], h[3]);
  *(ushort4*)(base + (((ls + 4) ^ sw) << 4)) = make_ushort4(l[0], l[1], l[2], l[3]);
}

// ---------------------------------------------------------------------------
// Kernel 0: hcw partials (unchanged, verified)
// ---------------------------------------------------------------------------
__global__ __launch_bounds__(256) void k_hcw(
    const float* __restrict__ hc, const float* __restrict__ Wa,
    float* __restrict__ part)
{
  const int jt = blockIdx.x, bt = blockIdx.y, kc = blockIdx.z;
  const int t = threadIdx.x;
  const int b0 = bt * 16;
  const int kb = kc * 256;
  __shared__ float As[BK][20];
  __shared__ float Bs[BK][256];
  const int tb = t & 3, tj = t >> 2;
  float acc[4][4] = {{0.f}};
  const float* brow = Wa + (size_t)(jt * 256 + t) * (2 * Hdim) + kb;
  const int r = t & 15, kq = t >> 4;
  for (int k0 = 0; k0 < 256; k0 += BK) {
    float4 bld[8];
    #pragma unroll
    for (int q = 0; q < 8; ++q) bld[q] = *(const float4*)(brow + k0 + q * 4);
    float4 ald = make_float4(0.f, 0.f, 0.f, 0.f);
    if (t < 128) ald = *(const float4*)(hc + (size_t)(b0 + r) * Hdim + kb + k0 + kq * 4);
    __syncthreads();
    #pragma unroll
    for (int q = 0; q < 8; ++q)
      #pragma unroll
      for (int e = 0; e < 4; ++e)
        Bs[q * 4 + e][t] = ((const float*)&bld[q])[e];
    if (t < 128) {
      #pragma unroll
      for (int e = 0; e < 4; ++e) As[kq * 4 + e][r] = ((const float*)&ald)[e];
    }
    __syncthreads();
    #pragma unroll 8
    for (int k = 0; k < BK; ++k) {
      const float4 av = *(const float4*)&As[k][tb * 4];
      const float4 bv = *(const float4*)&Bs[k][tj * 4];
      const float A4[4] = {av.x, av.y, av.z, av.w};
      const float B4[4] = {bv.x, bv.y, bv.z, bv.w};
      #pragma unroll
      for (int i = 0; i < 4; ++i)
        #pragma unroll
        for (int jj = 0; jj < 4; ++jj)
          acc[i][jj] = fmaf(A4[i], B4[jj], acc[i][jj]);
    }
  }
  float* outp = part + (size_t)kc * (Bdim * Hdim);
  #pragma unroll
  for (int i = 0; i < 4; ++i)
    #pragma unroll
    for (int jj = 0; jj < 4; ++jj)
      outp[(size_t)(b0 + tb * 4 + i) * Hdim + jt * 256 + tj * 4 + jj] = acc[i][jj];
}

// ---------------------------------------------------------------------------
// Kernel 1 v2 (MFMA): grid (8 jt, 64 bg), block 512 (8 waves: 4M x 2N).
// Tile M=256 (4 b), N=128 j, K-step 32. Staging = pure global_load_lds DMA
// from pre-split, pre-swizzled apre/wsp. LDS 48 KB -> 2 blocks/CU.
// ---------------------------------------------------------------------------
__global__ __launch_bounds__(512, 4) void k_scores_mfma2(
    const unsigned short* __restrict__ apre, const unsigned short* __restrict__ wsp,
    const float* __restrict__ ba, const float* __restrict__ v,
    float* __restrict__ ws_scores, const float* __restrict__ part)
{
  const int jt = blockIdx.x;           // 0..7
  const int bg = blockIdx.y;           // 0..63 ; b0 = bg*4
  const int t = threadIdx.x;
  const int lane = t & 63, wv = t >> 6;
  const int wm = wv >> 1, wn = wv & 1; // wave tile 64x64

  __shared__ uint4 ldsv[49152 / 16];   // A: 32 KB, B: 16 KB
  char* lds = (char*)ldsv;

  // frag read byte-offsets (swizzle on read; data pre-inverse-swizzled)
  const int s0 = lane >> 4;
  int aoff[4][2], boff[4][2];
  #pragma unroll
  for (int mt = 0; mt < 4; ++mt) {
    const int row = wm * 64 + mt * 16 + (lane & 15);
    aoff[mt][0] = row * 128 + ((s0 ^ (row & 7)) << 4);
    aoff[mt][1] = row * 128 + (((s0 + 4) ^ (row & 7)) << 4);
  }
  #pragma unroll
  for (int nt = 0; nt < 4; ++nt) {
    const int row = wn * 64 + nt * 16 + (lane & 15);
    boff[nt][0] = 32768 + row * 128 + ((s0 ^ (row & 7)) << 4);
    boff[nt][1] = 32768 + row * 128 + (((s0 + 4) ^ (row & 7)) << 4);
  }

  f32x4 acc[4][4];
  #pragma unroll
  for (int mt = 0; mt < 4; ++mt)
    #pragma unroll
    for (int nt = 0; nt < 4; ++nt) {
      f32x4 z = {0.f, 0.f, 0.f, 0.f};
      acc[mt][nt] = z;
    }

  const char* aB = (const char*)apre + ((size_t)bg << 20) + wv * 4096 + (lane << 4);
  const char* bB = (const char*)wsp + ((size_t)jt << 19) + wv * 2048 + (lane << 4);
  char* aL = lds + wv * 4096;
  char* bL = lds + 32768 + wv * 2048;

  for (int kc = 0; kc < 32; ++kc) {
    __syncthreads();                    // prev compute done; LDS writable
    const char* ac = aB + ((size_t)kc << 15);
    const char* bc = bB + ((size_t)kc << 14);
#if HAS_GLL
    gll16(ac,        aL);
    gll16(ac + 1024, aL + 1024);
    gll16(ac + 2048, aL + 2048);
    gll16(ac + 3072, aL + 3072);
    gll16(bc,        bL);
    gll16(bc + 1024, bL + 1024);
    asm volatile("s_waitcnt vmcnt(0)" ::: "memory");
#else
    #pragma unroll
    for (int q = 0; q < 4; ++q)
      *(uint4*)(aL + q * 1024 + (lane << 4)) = *(const uint4*)(ac + q * 1024);
    #pragma unroll
    for (int q = 0; q < 2; ++q)
      *(uint4*)(bL + q * 1024 + (lane << 4)) = *(const uint4*)(bc + q * 1024);
#endif
    __syncthreads();                    // tile visible (drains vmcnt/lgkmcnt)

    bf16x8 bfr[4][2];
    #pragma unroll
    for (int nt = 0; nt < 4; ++nt) {
      bfr[nt][0] = *(const bf16x8*)(lds + boff[nt][0]);
      bfr[nt][1] = *(const bf16x8*)(lds + boff[nt][1]);
    }
    #pragma unroll
    for (int mt = 0; mt < 4; ++mt) {
      const bf16x8 ah = *(const bf16x8*)(lds + aoff[mt][0]);
      const bf16x8 al = *(const bf16x8*)(lds + aoff[mt][1]);
      #pragma unroll
      for (int nt = 0; nt < 4; ++nt) {
        acc[mt][nt] = __builtin_amdgcn_mfma_f32_16x16x32_bf16(ah, bfr[nt][0], acc[mt][nt], 0, 0, 0);
        acc[mt][nt] = __builtin_amdgcn_mfma_f32_16x16x32_bf16(al, bfr[nt][0], acc[mt][nt], 0, 0, 0);
        acc[mt][nt] = __builtin_amdgcn_mfma_f32_16x16x32_bf16(ah, bfr[nt][1], acc[mt][nt], 0, 0, 0);
      }
    }
  }

  // ---- epilogue ----
  __syncthreads();                      // done reading LDS tiles
  float* f = (float*)ldsv;
  float* hcw_s = f;                     // [4 b][128 j]
  float* v_s   = f + 512;               // [128]
  float* red   = f + 640;               // [2 wn][256 rows]
  {
    const int bb = t >> 7, jj = t & 127;           // one element per thread
    const int jg = jt * 128 + jj;
    float s = ba[jg];
    #pragma unroll
    for (int kc = 0; kc < KC; ++kc)
      s += part[(size_t)kc * (Bdim * Hdim) + (size_t)(bg * 4 + bb) * Hdim + jg];
    hcw_s[t] = s;
    if (t < 128) v_s[t] = v[jt * 128 + t];
  }
  __syncthreads();

  float sred[4][4];
  #pragma unroll
  for (int mt = 0; mt < 4; ++mt)
    #pragma unroll
    for (int r = 0; r < 4; ++r) sred[mt][r] = 0.f;
  #pragma unroll
  for (int nt = 0; nt < 4; ++nt) {
    const int col = wn * 64 + nt * 16 + (lane & 15);
    const float hw = hcw_s[wm * 128 + col];        // wave's rows all in b_loc = wm
    const float vj = v_s[col];
    #pragma unroll
    for (int mt = 0; mt < 4; ++mt)
      #pragma unroll
      for (int r = 0; r < 4; ++r)
        sred[mt][r] = fmaf(vj, tanhf(((const float*)&acc[mt][nt])[r] + hw), sred[mt][r]);
  }
  #pragma unroll
  for (int mt = 0; mt < 4; ++mt)
    #pragma unroll
    for (int r = 0; r < 4; ++r) {
      float x = sred[mt][r];
      x += __shfl_xor(x, 1); x += __shfl_xor(x, 2);
      x += __shfl_xor(x, 4); x += __shfl_xor(x, 8);
      sred[mt][r] = x;
    }
  if ((lane & 15) == 0) {
    #pragma unroll
    for (int mt = 0; mt < 4; ++mt)
      #pragma unroll
      for (int r = 0; r < 4; ++r)
        red[wn * 256 + wm * 64 + mt * 16 + (lane >> 4) * 4 + r] = sred[mt][r];
  }
  __syncthreads();
  if (t < 256) {
    const float s = red[t] + red[256 + t];
    ws_scores[(size_t)jt * (Bdim * Wdim) + (size_t)(bg * 4 + (t >> 6)) * Wdim + (t & 63)] = s;
  }
}

// ---------------------------------------------------------------------------
// Old fp32 scores kernel (fallback) — verified path, writes 4 slots.
// ---------------------------------------------------------------------------
template<int USE_PART>
__global__ __launch_bounds__(256, 2) void k_scores(
    const float* __restrict__ inputs, const float* __restrict__ hc,
    const float* __restrict__ Wa, const float* __restrict__ ba,
    const float* __restrict__ v, const int* __restrict__ slen,
    float* __restrict__ ws_scores, const float* __restrict__ part)
{
  const int jt = blockIdx.x;
  const int b0 = blockIdx.y * 2;
  const int t = threadIdx.x;
  __shared__ float smem[SMEM_F];
  float* Bsb = smem + AS_F;

  const int tw = t & 15, tj = t >> 4;
  const int w0 = tw * 8, j0 = tj * 16;
  const int awp = w0 + 4 * (tw >> 2);

  const int ar = t >> 1, ah = t & 1;
  const int absub = ar >> 6;
  const int slA = slen[b0 + absub];
  const float* arow = inputs +
      ((size_t)(b0 + absub) * Sdim + slA - Wdim + (ar & 63)) * Hdim + ah * 16;
  const int aphys = ar + 4 * (ar >> 5);
  const float* brow = Wa + (size_t)(jt * JTILE + t) * (2 * Hdim) + Hdim;

  float acc[8][16];
  #pragma unroll
  for (int i = 0; i < 8; ++i)
    #pragma unroll
    for (int jj = 0; jj < 16; ++jj) acc[i][jj] = 0.f;

  for (int k0 = 0; k0 < Hdim; k0 += BK) {
    float4 a_ld[4];
    #pragma unroll
    for (int c = 0; c < 4; ++c) a_ld[c] = *(const float4*)(arow + k0 + c * 4);
    float4 b_ld[8];
    #pragma unroll
    for (int q = 0; q < 8; ++q) b_ld[q] = *(const float4*)(brow + k0 + q * 4);
    __syncthreads();
    #pragma unroll
    for (int c = 0; c < 4; ++c)
      #pragma unroll
      for (int e = 0; e < 4; ++e)
        smem[(ah * 16 + c * 4 + e) * ASTRIDE + aphys] = ((const float*)&a_ld[c])[e];
    #pragma unroll
    for (int q = 0; q < 8; ++q)
      #pragma unroll
      for (int e = 0; e < 4; ++e)
        Bsb[(q * 4 + e) * JTILE + t] = ((const float*)&b_ld[q])[e];
    __syncthreads();
    #pragma unroll 8
    for (int k = 0; k < BK; ++k) {
      const float* Ak = smem + k * ASTRIDE;
      const float* Bk = Bsb + k * JTILE;
      const float4 av0 = *(const float4*)(Ak + awp);
      const float4 av1 = *(const float4*)(Ak + awp + 4);
      const float4 bv0 = *(const float4*)(Bk + j0);
      const float4 bv1 = *(const float4*)(Bk + j0 + 4);
      const float4 bv2 = *(const float4*)(Bk + j0 + 8);
      const float4 bv3 = *(const float4*)(Bk + j0 + 12);
      const float A8[8]  = {av0.x, av0.y, av0.z, av0.w, av1.x, av1.y, av1.z, av1.w};
      const float B16[16] = {bv0.x, bv0.y, bv0.z, bv0.w, bv1.x, bv1.y, bv1.z, bv1.w,
                             bv2.x, bv2.y, bv2.z, bv2.w, bv3.x, bv3.y, bv3.z, bv3.w};
      #pragma unroll
      for (int wi = 0; wi < 8; ++wi)
        #pragma unroll
        for (int ji = 0; ji < 16; ++ji)
          acc[wi][ji] = fmaf(A8[wi], B16[ji], acc[wi][ji]);
    }
  }

  __syncthreads();
  const int j = jt * JTILE + t;
  if (USE_PART) {
    float h0 = ba[j], h1 = ba[j];
    #pragma unroll
    for (int kc = 0; kc < KC; ++kc) {
      h0 += part[(size_t)kc * (Bdim * Hdim) + (size_t)b0 * Hdim + j];
      h1 += part[(size_t)kc * (Bdim * Hdim) + (size_t)(b0 + 1) * Hdim + j];
    }
    smem[HCW_OFF + t] = h0;
    smem[HCW_OFF + 256 + t] = h1;
    smem[VS_OFF + t] = v[j];
  } else {
    for (int i = t; i < 2 * Hdim; i += 256) smem[HC0_OFF + i] = hc[(size_t)b0 * Hdim + i];
    __syncthreads();
    const float* w1row = Wa + (size_t)j * (2 * Hdim);
    float s0 = 0.f, s1 = 0.f;
    #pragma unroll 4
    for (int k = 0; k < Hdim; k += 4) {
      const float4 wv  = *(const float4*)(w1row + k);
      const float4 h0v = *(const float4*)(smem + HC0_OFF + k);
      const float4 h1v = *(const float4*)(smem + HC0_OFF + Hdim + k);
      s0 = fmaf(wv.x, h0v.x, s0); s0 = fmaf(wv.y, h0v.y, s0);
      s0 = fmaf(wv.z, h0v.z, s0); s0 = fmaf(wv.w, h0v.w, s0);
      s1 = fmaf(wv.x, h1v.x, s1); s1 = fmaf(wv.y, h1v.y, s1);
      s1 = fmaf(wv.z, h1v.z, s1); s1 = fmaf(wv.w, h1v.w, s1);
    }
    __syncthreads();
    smem[HCW_OFF + t] = s0 + ba[j];
    smem[HCW_OFF + 256 + t] = s1 + ba[j];
    smem[VS_OFF + t] = v[j];
  }
  __syncthreads();

  const int bsub = tw >> 3;
  float sloc[8] = {0.f, 0.f, 0.f, 0.f, 0.f, 0.f, 0.f, 0.f};
  #pragma unroll
  for (int ji = 0; ji < 16; ++ji) {
    const float hw = smem[HCW_OFF + bsub * 256 + j0 + ji];
    const float vj = smem[VS_OFF + j0 + ji];
    #pragma unroll
    for (int wi = 0; wi < 8; ++wi)
      sloc[wi] = fmaf(vj, tanhf(acc[wi][ji] + hw), sloc[wi]);
  }
  float* red = smem + AS_F;
  #pragma unroll
  for (int wi = 0; wi < 8; ++wi) red[tj * MTILE + w0 + wi] = sloc[wi];
  __syncthreads();
  if (t < MTILE) {
    float s = 0.f;
    #pragma unroll
    for (int p = 0; p < 16; ++p) s += red[p * MTILE + t];
    ws_scores[(size_t)jt * (Bdim * Wdim) + (size_t)(b0 + (t >> 6)) * Wdim + (t & 63)] = s;
  }
}

// ---------------------------------------------------------------------------
// Kernel 2: softmax + context + par. NPART = number of score partials to sum.
// ---------------------------------------------------------------------------
template<int NPART>
__global__ __launch_bounds__(256) void k_finish(
    const float* __restrict__ inputs, const int* __restrict__ slen,
    const int* __restrict__ parent, const float* __restrict__ ws_scores,
    float* __restrict__ out)
{
  const int b = blockIdx.x;
  const int c = blockIdx.y;
  const int t = threadIdx.x;
  const int sl = slen[b];
  __shared__ float attn[64];

  if (t < 64) {
    float s = 0.f;
    #pragma unroll
    for (int p = 0; p < NPART; ++p)
      s += ws_scores[(size_t)p * (Bdim * Wdim) + b * Wdim + t];
    float mx = s;
    #pragma unroll
    for (int off = 32; off > 0; off >>= 1) mx = fmaxf(mx, __shfl_xor(mx, off));
    const float e = __expf(s - mx);
    float sm = e;
    #pragma unroll
    for (int off = 32; off > 0; off >>= 1) sm += __shfl_xor(sm, off);
    const float a = e / sm;
    if (c == 0) out[b * Wdim + t] = a;
    attn[t] = a;
  }
  __syncthreads();

  const float* base = inputs + ((size_t)b * Sdim + sl - Wdim) * Hdim + c * 256;
  float a0 = 0.f;
  #pragma unroll 8
  for (int w = 0; w < Wdim; ++w)
    a0 = fmaf(attn[w], base[(size_t)w * Hdim + t], a0);
  out[Bdim * Wdim + (size_t)b * Hdim + c * 256 + t] = a0;

  const float* pr = inputs + ((size_t)b * Sdim + sl - parent[b] - 1) * Hdim + c * 256;
  out[Bdim * Wdim + Bdim * Hdim + (size_t)b * Hdim + c * 256 + t] = pr[t];
}

extern "C" void kernel_launch(void* const* d_in, const int* in_sizes, int n_in,
                              void* d_out, int out_size, void* d_ws, size_t ws_size,
                              hipStream_t stream) {
  const float* inputs = (const float*)d_in[0];
  const float* hc     = (const float*)d_in[1];
  const float* Wa     = (const float*)d_in[2];
  const float* ba     = (const float*)d_in[3];
  const float* v      = (const float*)d_in[4];
  const int*   slen   = (const int*)d_in[5];
  const int*   parent = (const int*)d_in[6];
  float* out = (float*)d_out;
  float* ws  = (float*)d_ws;
  float* part = ws + WS_SCORES_F;
  unsigned short* wsp  = (unsigned short*)(ws + WS_SCORES_F + WS_PART_F);
  unsigned short* apre = (unsigned short*)(ws + WS_SCORES_F + WS_PART_F + WS_WSP_F);

  if (ws_size >= WS_MFMA_BYTES && HAS_GLL) {
    k_wsplit<<<dim3(Hdim), 256, 0, stream>>>(Wa, wsp);
    k_aprep<<<dim3(Wdim, Bdim), 256, 0, stream>>>(inputs, slen, apre);
    k_hcw<<<dim3(NJT, 16, KC), 256, 0, stream>>>(hc, Wa, part);
    k_scores_mfma2<<<dim3(NJT2, Bdim / 4), 512, 0, stream>>>(
        apre, wsp, ba, v, ws, part);
    k_finish<NJT2><<<dim3(Bdim, 4), 256, 0, stream>>>(inputs, slen, parent, ws, out);
  } else if (ws_size >= WS_NEED_BYTES) {
    k_hcw<<<dim3(NJT, 16, KC), 256, 0, stream>>>(hc, Wa, part);
    k_scores<1><<<dim3(NJT, Bdim / 2), 256, 0, stream>>>(
        inputs, hc, Wa, ba, v, slen, ws, part);
    k_finish<NJT><<<dim3(Bdim, 4), 256, 0, stream>>>(inputs, slen, parent, ws, out);
  } else {
    k_scores<0><<<dim3(NJT, Bdim / 2), 256, 0, stream>>>(
        inputs, hc, Wa, ba, v, slen, ws, nullptr);
    k_finish<NJT><<<dim3(Bdim, 4), 256, 0, stream>>>(inputs, slen, parent, ws, out);
  }
}